// Round 4
// baseline (337.134 us; speedup 1.0000x reference)
//
#include <hip/hip_runtime.h>
#include <hip/hip_bf16.h>

typedef unsigned short u16;
typedef unsigned int u32;
typedef __attribute__((ext_vector_type(8))) short short8;   // 8 x bf16 (4 VGPRs)
typedef __attribute__((ext_vector_type(4))) float f32x4;

#define L_TOK 8192
#define BATCH 4
#define DIM 1024
#define KSEL 6144
#define NTOK (BATCH * L_TOK)   // 32768
#define NSEL (BATCH * KSEL)    // 24576
#define NUNSEL (NTOK - NSEL)   // 8192

// ---------- helpers ----------
__device__ __forceinline__ u16 f2bf(float f) {  // RNE fp32 -> bf16
    u32 u = __float_as_uint(f);
    return (u16)((u + 0x7fffu + ((u >> 16) & 1u)) >> 16);
}
__device__ __forceinline__ u32 cvt2(float a, float b) {  // pack 2 bf16 (RNE)
    __hip_bfloat162 h = __float22bfloat162_rn(float2{a, b});
    u32 r;
    __builtin_memcpy(&r, &h, 4);
    return r;
}
// gelu (tanh form) via hardware exp: 0.5*v*(1+tanh(z)) == v * sigmoid(2z)
__device__ __forceinline__ float gelu_fast(float v) {
    float z2 = 1.5957691216057308f * (v + 0.044715f * v * v * v);  // 2*sqrt(2/pi)*(...)
    return v / (1.0f + __expf(-z2));
}
__device__ __forceinline__ void async_copy16(const void* g, void* l) {
    __builtin_amdgcn_global_load_lds(
        (const __attribute__((address_space(1))) void*)g,
        (__attribute__((address_space(3))) void*)l, 16, 0, 0);
}

// ---------- 1) router scores (fp64 acc) + fused fp32->bf16 conversion of x ----------
__global__ __launch_bounds__(256) void score_kernel(const float* __restrict__ x,
                                                    const float* __restrict__ wr,
                                                    float* __restrict__ scores,
                                                    u16* __restrict__ xb) {
    int token = blockIdx.x * 4 + (threadIdx.x >> 6);
    int lane = threadIdx.x & 63;
    const float4* xr = (const float4*)(x + (size_t)token * DIM) + lane * 4;
    const float4* wp = (const float4*)wr + lane * 4;
    float4 v[4];
    double acc = 0.0;
#pragma unroll
    for (int c = 0; c < 4; ++c) {
        v[c] = xr[c];
        float4 wv = wp[c];
        acc += (double)v[c].x * wv.x + (double)v[c].y * wv.y +
               (double)v[c].z * wv.z + (double)v[c].w * wv.w;
    }
    if (xb) {  // identical RNE packing to a standalone cvt kernel
        union { short8 s[2]; u32 u[8]; } pk;
        pk.u[0] = cvt2(v[0].x, v[0].y); pk.u[1] = cvt2(v[0].z, v[0].w);
        pk.u[2] = cvt2(v[1].x, v[1].y); pk.u[3] = cvt2(v[1].z, v[1].w);
        pk.u[4] = cvt2(v[2].x, v[2].y); pk.u[5] = cvt2(v[2].z, v[2].w);
        pk.u[6] = cvt2(v[3].x, v[3].y); pk.u[7] = cvt2(v[3].z, v[3].w);
        short8* dst = (short8*)(xb + (size_t)token * DIM + lane * 16);
        dst[0] = pk.s[0]; dst[1] = pk.s[1];
    }
#pragma unroll
    for (int off = 32; off > 0; off >>= 1) acc += __shfl_down(acc, off, 64);
    if (lane == 0) scores[token] = (float)acc;
}

// ---------- 2) per-row top-k: radix select + stable tie-rank + index compaction ----------
__global__ __launch_bounds__(1024) void select_kernel(const float* __restrict__ scores,
                                                      int* __restrict__ mask,
                                                      int* __restrict__ sel_idx,
                                                      int* __restrict__ unsel_idx) {
    __shared__ u32 keys[L_TOK];      // 32 KB
    __shared__ int hist[256];
    __shared__ int g0[256], g1[256];
    __shared__ int wsum[16];
    __shared__ int wsum2[16];
    __shared__ int sel_digit, greater_cnt;
    const int b = blockIdx.x;
    const int tid = threadIdx.x;
    const int lane = tid & 63, wid = tid >> 6;
    const float* s = scores + (size_t)b * L_TOK;
    for (int i = tid; i < L_TOK; i += 1024) {
        u32 u = __float_as_uint(s[i]);
        keys[i] = (u & 0x80000000u) ? ~u : (u | 0x80000000u);  // order-preserving map
    }

    u32 prefix = 0;
    int need = KSEL;
#pragma unroll
    for (int pass = 0; pass < 4; ++pass) {
        const int shift = 24 - 8 * pass;
        const u32 pmask = (pass == 0) ? 0u : (0xFFFFFFFFu << (shift + 8));
        if (tid < 256) hist[tid] = 0;
        __syncthreads();   // hist zeroed; also covers keys[] visibility
        for (int i = tid; i < L_TOK; i += 1024) {
            u32 key = keys[i];
            if ((key & pmask) == prefix)
                atomicAdd(&hist[(key >> shift) & 0xffu], 1);
        }
        __syncthreads();
        // suffix-inclusive scan: G[d] = #active with digit >= d
        if (tid < 256) g0[tid] = hist[tid];
        __syncthreads();
        int* src = g0;
        int* dst = g1;
        for (int step = 1; step < 256; step <<= 1) {
            if (tid < 256) {
                int v = src[tid];
                if (tid + step < 256) v += src[tid + step];
                dst[tid] = v;
            }
            __syncthreads();
            int* t = src; src = dst; dst = t;
        }
        // d* = max{d : G[d] >= need}; # strictly greater = G[d*+1]
        if (tid < 256) {
            int Gd = src[tid];
            int Gn = (tid == 255) ? 0 : src[tid + 1];
            if (Gd >= need && Gn < need) { sel_digit = tid; greater_cnt = Gn; }
        }
        __syncthreads();
        prefix |= ((u32)sel_digit) << shift;
        need -= greater_cnt;
        __syncthreads();
    }
    const u32 T = prefix;        // exact k-th largest key
    const int need_eq = need;    // # of ==T tokens to take (lowest index first)

    // parallel stable rank of ==T keys: thread t owns contiguous chunk [8t, 8t+8)
    const int base = tid * 8;
    u32 kv[8];
    int eq = 0;
#pragma unroll
    for (int c = 0; c < 8; ++c) { kv[c] = keys[base + c]; eq += (kv[c] == T); }
    int inc = eq;   // wave-level inclusive scan of eq counts
#pragma unroll
    for (int off = 1; off < 64; off <<= 1) {
        int n = __shfl_up(inc, off, 64);
        if (lane >= off) inc += n;
    }
    if (lane == 63) wsum[wid] = inc;
    __syncthreads();
    int wbase = 0;
    for (int w = 0; w < wid; ++w) wbase += wsum[w];
    int rank = wbase + inc - eq;   // exclusive eq-rank at chunk start
    int sel[8];
#pragma unroll
    for (int c = 0; c < 8; ++c) {
        u32 key = kv[c];
        int se = 0;
        if (key > T) se = 1;
        else if (key == T) { se = (rank < need_eq) ? 1 : 0; rank++; }
        sel[c] = se;
    }
    int4* mp = (int4*)(mask + (size_t)b * L_TOK + base);
    mp[0] = int4{sel[0], sel[1], sel[2], sel[3]};
    mp[1] = int4{sel[4], sel[5], sel[6], sel[7]};

    // ---- stable compaction of selected / unselected token indices ----
    int cnt = 0;
#pragma unroll
    for (int c = 0; c < 8; ++c) cnt += sel[c];
    int inc2 = cnt;
#pragma unroll
    for (int off = 1; off < 64; off <<= 1) {
        int n = __shfl_up(inc2, off, 64);
        if (lane >= off) inc2 += n;
    }
    if (lane == 63) wsum2[wid] = inc2;
    __syncthreads();
    int wb2 = 0;
    for (int w = 0; w < wid; ++w) wb2 += wsum2[w];
    int pos = wb2 + inc2 - cnt;    // selected exclusive prefix at chunk start
    int up = base - pos;           // unselected exclusive prefix
    int* si = sel_idx + (size_t)b * KSEL;
    int* ui = unsel_idx + (size_t)b * (L_TOK - KSEL);
#pragma unroll
    for (int c = 0; c < 8; ++c) {
        int gtok = b * L_TOK + base + c;   // global token id
        if (sel[c]) si[pos++] = gtok;
        else        ui[up++]  = gtok;
    }
}

// ---------- 3) convert+transpose w_block (fp32) -> WT bf16 [n][k] ----------
__global__ __launch_bounds__(256) void transpose_kernel(const float* __restrict__ W,
                                                        u16* __restrict__ WT) {
    __shared__ u16 tile[32][33];
    int bx = blockIdx.x * 32, by = blockIdx.y * 32;
    int tx = threadIdx.x & 31, ty = threadIdx.x >> 5;  // 32 x 8
    for (int r = ty; r < 32; r += 8)
        tile[r][tx] = f2bf(W[(size_t)(by + r) * DIM + bx + tx]);
    __syncthreads();
    for (int r = ty; r < 32; r += 8)
        WT[(size_t)(bx + r) * DIM + by + tx] = tile[tx][r];
}

// ================= 4) depth-3 pipelined compacted-row GEMM =================
// BM=256 x BN=128, BK=32, 4 waves (2M x 2N), per-wave 128x64 (acc[8][4]).
// Triple-buffer, counted s_waitcnt vmcnt(12): tile t+1 is staged 2 FULL
// iterations before its wait -> slack > HBM latency (~900 cy, m126).
// Per-iter order: ds_reads -> MFMA (compiler interleaves lgkm waits, m97)
// -> lgkm(0) [WAR gate] -> barrier -> stage t+3 -> vmcnt(12) -> barrier.
// Swizzle (64B rows, bank-enumerated, 0-conflict verified round 3):
// phys_slot = q ^ ((row>>1)&3), applied on BOTH global source and ds_read
// (rule 21); LDS dest of global_load_lds stays linear.
#define PM 256
#define PN 128
#define PK 32
#define PNT (DIM / PK)    // 32 K-steps
#define ASZ (PM * PK)     // 8192 u16 = 16 KB per buffer
#define BSZ (PN * PK)     // 4096 u16 =  8 KB per buffer

__global__ __launch_bounds__(256, 2) void gemm_idx_kernel(const u16* __restrict__ Xb,
                                                          const u16* __restrict__ WT,
                                                          const int* __restrict__ sel_idx,
                                                          float* __restrict__ out) {
    __shared__ alignas(16) u16 As[3][ASZ];   // 48 KB
    __shared__ alignas(16) u16 Bs[3][BSZ];   // 24 KB
    const int tid = threadIdx.x;
    const int wave = tid >> 6, lane = tid & 63;
    const int wm = wave >> 1, wn = wave & 1;
    const int rowbase = blockIdx.x * PM;      // into sel_idx space
    const int colbase = blockIdx.y * PN;
    const int q = lane >> 4, mrow = lane & 15;

    f32x4 acc[8][4] = {};

    // hoisted staging descriptors: per-lane (inverse-swizzled) global source,
    // linear LDS dest (wave-uniform base + lane*16 — required by global_load_lds)
    const u16* aS[4]; int aO[4];
    const u16* bS[2]; int bO[2];
#pragma unroll
    for (int j = 0; j < 4; ++j) {
        int c = tid + 256 * j;               // 1024 chunks: 256 rows x 4 slots
        int row = c >> 2, slot = c & 3;
        int ss = slot ^ ((row >> 1) & 3);    // same involution as the read side
        int tok = sel_idx[rowbase + row];    // gather: selected token id
        aS[j] = Xb + (size_t)tok * DIM + ss * 8;
        aO[j] = c * 8;
    }
#pragma unroll
    for (int j = 0; j < 2; ++j) {
        int c = tid + 256 * j;               // 512 chunks: 128 rows x 4 slots
        int row = c >> 2, slot = c & 3;
        int ss = slot ^ ((row >> 1) & 3);
        bS[j] = WT + (size_t)(colbase + row) * DIM + ss * 8;
        bO[j] = c * 8;
    }

    // prologue: stage tiles 0,1,2 (18 load-instrs), wait for tile 0's 6
#pragma unroll
    for (int tt = 0; tt < 3; ++tt) {
        int ko = tt * PK;
#pragma unroll
        for (int j = 0; j < 4; ++j) async_copy16(aS[j] + ko, &As[tt][aO[j]]);
#pragma unroll
        for (int j = 0; j < 2; ++j) async_copy16(bS[j] + ko, &Bs[tt][bO[j]]);
    }
    asm volatile("s_waitcnt vmcnt(12)" ::: "memory");
    __builtin_amdgcn_sched_barrier(0);
    __builtin_amdgcn_s_barrier();
    __builtin_amdgcn_sched_barrier(0);

    // swizzled k-slot offset: (r>>1)&3 == (mrow>>1)&3 for every frag row
    // (wm*128, wn*64, i*16, j*16 all contribute 0 mod 4 to r>>1) -> lane-const
    const int xorv = (q ^ ((mrow >> 1) & 3)) * 8;

    int cur = 0;   // t % 3
    for (int t = 0; t < PNT; ++t) {
        const u16* Ac = As[cur];
        const u16* Bc = Bs[cur];
        short8 a[8], b[4];
#pragma unroll
        for (int i = 0; i < 8; ++i) {
            int r = wm * 128 + i * 16 + mrow;
            a[i] = *(const short8*)(Ac + r * PK + xorv);
        }
#pragma unroll
        for (int j = 0; j < 4; ++j) {
            int r = wn * 64 + j * 16 + mrow;
            b[j] = *(const short8*)(Bc + r * PK + xorv);
        }
        // NO hard fence here: compiler interleaves MFMA with fine-grained
        // lgkmcnt waits as the frags land (m97 asm evidence)
        __builtin_amdgcn_s_setprio(1);
#pragma unroll
        for (int i = 0; i < 8; ++i)
#pragma unroll
            for (int j = 0; j < 4; ++j)
                acc[i][j] = __builtin_amdgcn_mfma_f32_16x16x32_bf16(a[i], b[j], acc[i][j], 0, 0, 0);
        __builtin_amdgcn_s_setprio(0);
        __builtin_amdgcn_sched_barrier(0);

        // WAR gate: this wave's ds_reads all complete (DS returns in order),
        // then workgroup barrier before anyone overwrites buf[cur]
        asm volatile("s_waitcnt lgkmcnt(0)" ::: "memory");
        __builtin_amdgcn_sched_barrier(0);
        __builtin_amdgcn_s_barrier();
        __builtin_amdgcn_sched_barrier(0);

        // stage tile t+3 into the just-consumed buffer (tail: re-stage t,
        // L2-hit, keeps the vmcnt ledger uniform at 6 load-instrs/tile)
        {
            int ts = (t + 3 < PNT) ? t + 3 : t;
            int ko = ts * PK;
            u16* Aw = As[cur];
            u16* Bw = Bs[cur];
#pragma unroll
            for (int j = 0; j < 4; ++j) async_copy16(aS[j] + ko, Aw + aO[j]);
#pragma unroll
            for (int j = 0; j < 2; ++j) async_copy16(bS[j] + ko, Bw + bO[j]);
        }
        __builtin_amdgcn_sched_barrier(0);

        // counted wait: newest 12 = tiles t+2,t+3 may be in flight; everything
        // through tile t+1 (staged 2 iters ago) has landed
        asm volatile("s_waitcnt vmcnt(12)" ::: "memory");
        __builtin_amdgcn_sched_barrier(0);
        __builtin_amdgcn_s_barrier();
        __builtin_amdgcn_sched_barrier(0);

        cur = (cur == 2) ? 0 : cur + 1;
    }

    // epilogue: gelu + scatter via sel_idx
#pragma unroll
    for (int i = 0; i < 8; ++i) {
#pragma unroll
        for (int rr = 0; rr < 4; ++rr) {
            int lrow = wm * 128 + i * 16 + q * 4 + rr;
            int tok = sel_idx[rowbase + lrow];
#pragma unroll
            for (int j = 0; j < 4; ++j) {
                float g = gelu_fast(acc[i][j][rr]);
                int col = colbase + wn * 64 + j * 16 + mrow;
                out[(size_t)tok * DIM + col] = g;
            }
        }
    }
}

// ---------- 4-fallback) mask-based GEMM with in-loop fp32->bf16 (small ws) ----------
#define FBM 128
#define FBN 128
#define FBK 32
__global__ __launch_bounds__(256) void gemm_f32_kernel(const float* __restrict__ X,
                                                       const u16* __restrict__ WT,
                                                       const int* __restrict__ mask,
                                                       float* __restrict__ out) {
    __shared__ alignas(16) u16 Asf[FBM * FBK];
    __shared__ alignas(16) u16 Bsf[FBN * FBK];
    const int tid = threadIdx.x;
    const int wave = tid >> 6, lane = tid & 63;
    const int wm = wave >> 1, wn = wave & 1;
    const size_t rowbase = (size_t)blockIdx.x * FBM;
    const int colbase = blockIdx.y * FBN;

    f32x4 acc[4][4] = {};

    const int cb0 = tid, cb1 = tid + 256;
    const int br0 = cb0 >> 2, bk0 = (cb0 & 3) * 8;
    const int br1 = cb1 >> 2, bk1 = (cb1 & 3) * 8;
    const int arow = tid >> 1, ahalf = tid & 1;
    const int q = lane >> 4, mrow = lane & 15;

    for (int kt = 0; kt < DIM; kt += FBK) {
        async_copy16(WT + (size_t)(colbase + br0) * DIM + kt + bk0, Bsf + cb0 * 8);
        async_copy16(WT + (size_t)(colbase + br1) * DIM + kt + bk1, Bsf + cb1 * 8);

        const float4* xp = (const float4*)(X + (rowbase + arow) * DIM + kt + ahalf * 16);
        float4 v0 = xp[0], v1 = xp[1], v2 = xp[2], v3 = xp[3];
        union { short8 s[2]; u32 u[8]; } pk;
        pk.u[0] = cvt2(v0.x, v0.y); pk.u[1] = cvt2(v0.z, v0.w);
        pk.u[2] = cvt2(v1.x, v1.y); pk.u[3] = cvt2(v1.z, v1.w);
        pk.u[4] = cvt2(v2.x, v2.y); pk.u[5] = cvt2(v2.z, v2.w);
        pk.u[6] = cvt2(v3.x, v3.y); pk.u[7] = cvt2(v3.z, v3.w);
        *(short8*)(Asf + arow * FBK + ahalf * 16)     = pk.s[0];
        *(short8*)(Asf + arow * FBK + ahalf * 16 + 8) = pk.s[1];

        __syncthreads();

        short8 a[4], b[4];
#pragma unroll
        for (int i = 0; i < 4; ++i)
            a[i] = *(const short8*)(Asf + (wm * 64 + i * 16 + mrow) * FBK + q * 8);
#pragma unroll
        for (int j = 0; j < 4; ++j)
            b[j] = *(const short8*)(Bsf + (wn * 64 + j * 16 + mrow) * FBK + q * 8);
#pragma unroll
        for (int i = 0; i < 4; ++i)
#pragma unroll
            for (int j = 0; j < 4; ++j)
                acc[i][j] = __builtin_amdgcn_mfma_f32_16x16x32_bf16(a[i], b[j], acc[i][j], 0, 0, 0);
        __syncthreads();
    }

#pragma unroll
    for (int i = 0; i < 4; ++i) {
#pragma unroll
        for (int r = 0; r < 4; ++r) {
            size_t grow = rowbase + wm * 64 + i * 16 + q * 4 + r;
            if (mask[grow]) {
#pragma unroll
                for (int j = 0; j < 4; ++j) {
                    float g = gelu_fast(acc[i][j][r]);
                    int col = colbase + wn * 64 + j * 16 + mrow;
                    out[grow * DIM + col] = g;
                }
            }
        }
    }
}

// ---------- 5) pass-through for unselected tokens via compacted index list ----------
__global__ __launch_bounds__(256) void passthrough_idx_kernel(const float* __restrict__ x,
                                                              const int* __restrict__ unsel_idx,
                                                              float* __restrict__ out) {
    int tok = unsel_idx[blockIdx.x];
    size_t c = (size_t)tok * (DIM / 4) + threadIdx.x;  // float4 units, 256/token
    ((float4*)out)[c] = ((const float4*)x)[c];
}

extern "C" void kernel_launch(void* const* d_in, const int* in_sizes, int n_in,
                              void* d_out, int out_size, void* d_ws, size_t ws_size,
                              hipStream_t stream) {
    const float* x  = (const float*)d_in[0];   // [4,8192,1024] fp32
    const float* wr = (const float*)d_in[1];   // [1024] fp32
    const float* wb = (const float*)d_in[2];   // [1024,1024] fp32
    float* out = (float*)d_out;

    char* ws = (char*)d_ws;
    float* scores    = (float*)ws;                            // 128 KB
    int*   mask      = (int*)(ws + (size_t)NTOK * 4);         // 128 KB
    int*   sel_idx   = (int*)(ws + (size_t)NTOK * 8);         // 96 KB
    int*   unsel_idx = (int*)(ws + (size_t)NTOK * 8 + (size_t)NSEL * 4);  // 32 KB
    char*  after_idx = ws + (size_t)NTOK * 8 + (size_t)NTOK * 4;          // = 384 KB
    u16*   WT        = (u16*)after_idx;                       // 2 MB bf16
    u16*   Xb        = (u16*)(after_idx + (size_t)DIM * DIM * 2);  // 64 MB bf16

    const size_t need_ws = (size_t)NTOK * 12 + (size_t)DIM * DIM * 2
                         + (size_t)NTOK * DIM * 2;
    const bool big = (ws_size >= need_ws);

    score_kernel<<<NTOK / 4, 256, 0, stream>>>(x, wr, scores, big ? Xb : nullptr);
    select_kernel<<<BATCH, 1024, 0, stream>>>(scores, mask, sel_idx, unsel_idx);
    transpose_kernel<<<dim3(DIM / 32, DIM / 32), 256, 0, stream>>>(wb, WT);
    if (big) {
        gemm_idx_kernel<<<dim3(NSEL / PM, DIM / PN), 256, 0, stream>>>(Xb, WT, sel_idx, out);
    } else {
        gemm_f32_kernel<<<dim3(NTOK / FBM, DIM / FBN), 256, 0, stream>>>(x, WT, mask, out);
    }
    passthrough_idx_kernel<<<NUNSEL, 256, 0, stream>>>(x, unsel_idx, out);
}

// Round 5
// 325.767 us; speedup vs baseline: 1.0349x; 1.0349x over previous
//
#include <hip/hip_runtime.h>
#include <hip/hip_bf16.h>

typedef unsigned short u16;
typedef unsigned int u32;
typedef __attribute__((ext_vector_type(8))) short short8;   // 8 x bf16 (4 VGPRs)
typedef __attribute__((ext_vector_type(4))) float f32x4;

#define L_TOK 8192
#define BATCH 4
#define DIM 1024
#define KSEL 6144
#define NTOK (BATCH * L_TOK)   // 32768
#define NSEL (BATCH * KSEL)    // 24576
#define NUNSEL (NTOK - NSEL)   // 8192

// ---------- helpers ----------
__device__ __forceinline__ u16 f2bf(float f) {  // RNE fp32 -> bf16
    u32 u = __float_as_uint(f);
    return (u16)((u + 0x7fffu + ((u >> 16) & 1u)) >> 16);
}
__device__ __forceinline__ u32 cvt2(float a, float b) {  // pack 2 bf16 (RNE)
    __hip_bfloat162 h = __float22bfloat162_rn(float2{a, b});
    u32 r;
    __builtin_memcpy(&r, &h, 4);
    return r;
}
// gelu (tanh form) via hardware exp: 0.5*v*(1+tanh(z)) == v * sigmoid(2z)
__device__ __forceinline__ float gelu_fast(float v) {
    float z2 = 1.5957691216057308f * (v + 0.044715f * v * v * v);  // 2*sqrt(2/pi)*(...)
    return v / (1.0f + __expf(-z2));
}
__device__ __forceinline__ void async_copy16(const void* g, void* l) {
    __builtin_amdgcn_global_load_lds(
        (const __attribute__((address_space(1))) void*)g,
        (__attribute__((address_space(3))) void*)l, 16, 0, 0);
}

// ---------- 1) router scores (fp64 acc) + fused fp32->bf16 conversion of x ----------
__global__ __launch_bounds__(256) void score_kernel(const float* __restrict__ x,
                                                    const float* __restrict__ wr,
                                                    float* __restrict__ scores,
                                                    u16* __restrict__ xb) {
    int token = blockIdx.x * 4 + (threadIdx.x >> 6);
    int lane = threadIdx.x & 63;
    const float4* xr = (const float4*)(x + (size_t)token * DIM) + lane * 4;
    const float4* wp = (const float4*)wr + lane * 4;
    float4 v[4];
    double acc = 0.0;
#pragma unroll
    for (int c = 0; c < 4; ++c) {
        v[c] = xr[c];
        float4 wv = wp[c];
        acc += (double)v[c].x * wv.x + (double)v[c].y * wv.y +
               (double)v[c].z * wv.z + (double)v[c].w * wv.w;
    }
    if (xb) {  // identical RNE packing to a standalone cvt kernel
        union { short8 s[2]; u32 u[8]; } pk;
        pk.u[0] = cvt2(v[0].x, v[0].y); pk.u[1] = cvt2(v[0].z, v[0].w);
        pk.u[2] = cvt2(v[1].x, v[1].y); pk.u[3] = cvt2(v[1].z, v[1].w);
        pk.u[4] = cvt2(v[2].x, v[2].y); pk.u[5] = cvt2(v[2].z, v[2].w);
        pk.u[6] = cvt2(v[3].x, v[3].y); pk.u[7] = cvt2(v[3].z, v[3].w);
        short8* dst = (short8*)(xb + (size_t)token * DIM + lane * 16);
        dst[0] = pk.s[0]; dst[1] = pk.s[1];
    }
#pragma unroll
    for (int off = 32; off > 0; off >>= 1) acc += __shfl_down(acc, off, 64);
    if (lane == 0) scores[token] = (float)acc;
}

// ---------- 2) per-row top-k: radix select + stable tie-rank + index compaction ----------
__global__ __launch_bounds__(1024) void select_kernel(const float* __restrict__ scores,
                                                      int* __restrict__ mask,
                                                      int* __restrict__ sel_idx,
                                                      int* __restrict__ unsel_idx) {
    __shared__ u32 keys[L_TOK];      // 32 KB
    __shared__ int hist[256];
    __shared__ int g0[256], g1[256];
    __shared__ int wsum[16];
    __shared__ int wsum2[16];
    __shared__ int sel_digit, greater_cnt;
    const int b = blockIdx.x;
    const int tid = threadIdx.x;
    const int lane = tid & 63, wid = tid >> 6;
    const float* s = scores + (size_t)b * L_TOK;
    for (int i = tid; i < L_TOK; i += 1024) {
        u32 u = __float_as_uint(s[i]);
        keys[i] = (u & 0x80000000u) ? ~u : (u | 0x80000000u);  // order-preserving map
    }

    u32 prefix = 0;
    int need = KSEL;
#pragma unroll
    for (int pass = 0; pass < 4; ++pass) {
        const int shift = 24 - 8 * pass;
        const u32 pmask = (pass == 0) ? 0u : (0xFFFFFFFFu << (shift + 8));
        if (tid < 256) hist[tid] = 0;
        __syncthreads();   // hist zeroed; also covers keys[] visibility
        for (int i = tid; i < L_TOK; i += 1024) {
            u32 key = keys[i];
            if ((key & pmask) == prefix)
                atomicAdd(&hist[(key >> shift) & 0xffu], 1);
        }
        __syncthreads();
        // suffix-inclusive scan: G[d] = #active with digit >= d
        if (tid < 256) g0[tid] = hist[tid];
        __syncthreads();
        int* src = g0;
        int* dst = g1;
        for (int step = 1; step < 256; step <<= 1) {
            if (tid < 256) {
                int v = src[tid];
                if (tid + step < 256) v += src[tid + step];
                dst[tid] = v;
            }
            __syncthreads();
            int* t = src; src = dst; dst = t;
        }
        // d* = max{d : G[d] >= need}; # strictly greater = G[d*+1]
        if (tid < 256) {
            int Gd = src[tid];
            int Gn = (tid == 255) ? 0 : src[tid + 1];
            if (Gd >= need && Gn < need) { sel_digit = tid; greater_cnt = Gn; }
        }
        __syncthreads();
        prefix |= ((u32)sel_digit) << shift;
        need -= greater_cnt;
        __syncthreads();
    }
    const u32 T = prefix;        // exact k-th largest key
    const int need_eq = need;    // # of ==T tokens to take (lowest index first)

    // parallel stable rank of ==T keys: thread t owns contiguous chunk [8t, 8t+8)
    const int base = tid * 8;
    u32 kv[8];
    int eq = 0;
#pragma unroll
    for (int c = 0; c < 8; ++c) { kv[c] = keys[base + c]; eq += (kv[c] == T); }
    int inc = eq;   // wave-level inclusive scan of eq counts
#pragma unroll
    for (int off = 1; off < 64; off <<= 1) {
        int n = __shfl_up(inc, off, 64);
        if (lane >= off) inc += n;
    }
    if (lane == 63) wsum[wid] = inc;
    __syncthreads();
    int wbase = 0;
    for (int w = 0; w < wid; ++w) wbase += wsum[w];
    int rank = wbase + inc - eq;   // exclusive eq-rank at chunk start
    int sel[8];
#pragma unroll
    for (int c = 0; c < 8; ++c) {
        u32 key = kv[c];
        int se = 0;
        if (key > T) se = 1;
        else if (key == T) { se = (rank < need_eq) ? 1 : 0; rank++; }
        sel[c] = se;
    }
    int4* mp = (int4*)(mask + (size_t)b * L_TOK + base);
    mp[0] = int4{sel[0], sel[1], sel[2], sel[3]};
    mp[1] = int4{sel[4], sel[5], sel[6], sel[7]};

    // ---- stable compaction of selected / unselected token indices ----
    int cnt = 0;
#pragma unroll
    for (int c = 0; c < 8; ++c) cnt += sel[c];
    int inc2 = cnt;
#pragma unroll
    for (int off = 1; off < 64; off <<= 1) {
        int n = __shfl_up(inc2, off, 64);
        if (lane >= off) inc2 += n;
    }
    if (lane == 63) wsum2[wid] = inc2;
    __syncthreads();
    int wb2 = 0;
    for (int w = 0; w < wid; ++w) wb2 += wsum2[w];
    int pos = wb2 + inc2 - cnt;    // selected exclusive prefix at chunk start
    int up = base - pos;           // unselected exclusive prefix
    int* si = sel_idx + (size_t)b * KSEL;
    int* ui = unsel_idx + (size_t)b * (L_TOK - KSEL);
#pragma unroll
    for (int c = 0; c < 8; ++c) {
        int gtok = b * L_TOK + base + c;   // global token id
        if (sel[c]) si[pos++] = gtok;
        else        ui[up++]  = gtok;
    }
}

// ---------- 3) convert+transpose w_block (fp32) -> WT bf16 [n][k] ----------
__global__ __launch_bounds__(256) void transpose_kernel(const float* __restrict__ W,
                                                        u16* __restrict__ WT) {
    __shared__ u16 tile[32][33];
    int bx = blockIdx.x * 32, by = blockIdx.y * 32;
    int tx = threadIdx.x & 31, ty = threadIdx.x >> 5;  // 32 x 8
    for (int r = ty; r < 32; r += 8)
        tile[r][tx] = f2bf(W[(size_t)(by + r) * DIM + bx + tx]);
    __syncthreads();
    for (int r = ty; r < 32; r += 8)
        WT[(size_t)(bx + r) * DIM + by + tx] = tile[tx][r];
}

// ================= 4) compacted-row GEMM: 256x128 tile, SIMPLE schedule =================
// Lesson from rounds 2-4: asm-fenced pipelines (counted vmcnt, sched_barrier,
// depth-2/3) all LOSE to the plain-__syncthreads compiler-scheduled loop
// (81 vs 88-98 us) — regime gate: those techniques need a full 8-phase
// structure to pay. This kernel = round-1's proven simple schedule x the
// 256x128 geometry (per-wave 128x64, acc[8][4]): MFMA:ds_read cycle ratio
// rises from 155:192 (LDS-bound) to 310:288 (MFMA-bound), barrier count per
// output halves, grid = 768 = exactly 3 waves of 256 CUs.
// Swizzle: BK=64 (128B rows), phys_slot = slot ^ (row&7) — measured ZERO
// conflicts in round 1. Applied on global source + ds_read (rule 21);
// LDS dest of global_load_lds stays linear.
#define PM 256
#define PN 128
#define PK 64

__global__ __launch_bounds__(256, 2) void gemm_idx_kernel(const u16* __restrict__ Xb,
                                                          const u16* __restrict__ WT,
                                                          const int* __restrict__ sel_idx,
                                                          float* __restrict__ out) {
    __shared__ alignas(16) u16 As[PM * PK];   // 32 KB
    __shared__ alignas(16) u16 Bs[PN * PK];   // 16 KB
    const int tid = threadIdx.x;
    const int wave = tid >> 6, lane = tid & 63;
    const int wm = wave >> 1, wn = wave & 1;
    const int rowbase = blockIdx.x * PM;      // into sel_idx space
    const int colbase = blockIdx.y * PN;
    const int q = lane >> 4, mrow = lane & 15;

    f32x4 acc[8][4] = {};

    // staging descriptors (loop-invariant): A = 2048 16B chunks (8/thread),
    // B = 1024 chunks (4/thread). chunk c -> row = c>>3, slot = c&7;
    // global source pre-swizzled by the same involution as the read side.
    const u16* aS[8]; int aO[8];
    const u16* bS[4]; int bO[4];
#pragma unroll
    for (int j = 0; j < 8; ++j) {
        int c = tid + 256 * j;
        int row = c >> 3, slot = c & 7;
        int ss = slot ^ (row & 7);
        int tok = sel_idx[rowbase + row];    // gather: selected token id
        aS[j] = Xb + (size_t)tok * DIM + ss * 8;
        aO[j] = c * 8;
    }
#pragma unroll
    for (int j = 0; j < 4; ++j) {
        int c = tid + 256 * j;
        int row = c >> 3, slot = c & 7;
        int ss = slot ^ (row & 7);
        bS[j] = WT + (size_t)(colbase + row) * DIM + ss * 8;
        bO[j] = c * 8;
    }

    for (int kt = 0; kt < DIM; kt += PK) {
#pragma unroll
        for (int j = 0; j < 8; ++j) async_copy16(aS[j] + kt, As + aO[j]);
#pragma unroll
        for (int j = 0; j < 4; ++j) async_copy16(bS[j] + kt, Bs + bO[j]);
        __syncthreads();   // drains vmcnt before barrier -> tiles visible

#pragma unroll
        for (int kk = 0; kk < 2; ++kk) {
            const int xs = ((kk * 4 + q) ^ (mrow & 7)) * 8;   // swizzled k-slot
            short8 a[8], b[4];
#pragma unroll
            for (int i = 0; i < 8; ++i) {
                int r = wm * 128 + i * 16 + mrow;
                a[i] = *(const short8*)(As + r * PK + xs);
            }
#pragma unroll
            for (int j = 0; j < 4; ++j) {
                int r = wn * 64 + j * 16 + mrow;
                b[j] = *(const short8*)(Bs + r * PK + xs);
            }
#pragma unroll
            for (int i = 0; i < 8; ++i)
#pragma unroll
                for (int j = 0; j < 4; ++j)
                    acc[i][j] = __builtin_amdgcn_mfma_f32_16x16x32_bf16(a[i], b[j], acc[i][j], 0, 0, 0);
        }
        __syncthreads();
    }

    // epilogue: gelu + scatter via sel_idx
#pragma unroll
    for (int i = 0; i < 8; ++i) {
#pragma unroll
        for (int rr = 0; rr < 4; ++rr) {
            int lrow = wm * 128 + i * 16 + q * 4 + rr;
            int tok = sel_idx[rowbase + lrow];
#pragma unroll
            for (int j = 0; j < 4; ++j) {
                float g = gelu_fast(acc[i][j][rr]);
                int col = colbase + wn * 64 + j * 16 + mrow;
                out[(size_t)tok * DIM + col] = g;
            }
        }
    }
}

// ---------- 4-fallback) mask-based GEMM with in-loop fp32->bf16 (small ws) ----------
#define FBM 128
#define FBN 128
#define FBK 32
__global__ __launch_bounds__(256) void gemm_f32_kernel(const float* __restrict__ X,
                                                       const u16* __restrict__ WT,
                                                       const int* __restrict__ mask,
                                                       float* __restrict__ out) {
    __shared__ alignas(16) u16 Asf[FBM * FBK];
    __shared__ alignas(16) u16 Bsf[FBN * FBK];
    const int tid = threadIdx.x;
    const int wave = tid >> 6, lane = tid & 63;
    const int wm = wave >> 1, wn = wave & 1;
    const size_t rowbase = (size_t)blockIdx.x * FBM;
    const int colbase = blockIdx.y * FBN;

    f32x4 acc[4][4] = {};

    const int cb0 = tid, cb1 = tid + 256;
    const int br0 = cb0 >> 2, bk0 = (cb0 & 3) * 8;
    const int br1 = cb1 >> 2, bk1 = (cb1 & 3) * 8;
    const int arow = tid >> 1, ahalf = tid & 1;
    const int q = lane >> 4, mrow = lane & 15;

    for (int kt = 0; kt < DIM; kt += FBK) {
        async_copy16(WT + (size_t)(colbase + br0) * DIM + kt + bk0, Bsf + cb0 * 8);
        async_copy16(WT + (size_t)(colbase + br1) * DIM + kt + bk1, Bsf + cb1 * 8);

        const float4* xp = (const float4*)(X + (rowbase + arow) * DIM + kt + ahalf * 16);
        float4 v0 = xp[0], v1 = xp[1], v2 = xp[2], v3 = xp[3];
        union { short8 s[2]; u32 u[8]; } pk;
        pk.u[0] = cvt2(v0.x, v0.y); pk.u[1] = cvt2(v0.z, v0.w);
        pk.u[2] = cvt2(v1.x, v1.y); pk.u[3] = cvt2(v1.z, v1.w);
        pk.u[4] = cvt2(v2.x, v2.y); pk.u[5] = cvt2(v2.z, v2.w);
        pk.u[6] = cvt2(v3.x, v3.y); pk.u[7] = cvt2(v3.z, v3.w);
        *(short8*)(Asf + arow * FBK + ahalf * 16)     = pk.s[0];
        *(short8*)(Asf + arow * FBK + ahalf * 16 + 8) = pk.s[1];

        __syncthreads();

        short8 a[4], b[4];
#pragma unroll
        for (int i = 0; i < 4; ++i)
            a[i] = *(const short8*)(Asf + (wm * 64 + i * 16 + mrow) * FBK + q * 8);
#pragma unroll
        for (int j = 0; j < 4; ++j)
            b[j] = *(const short8*)(Bsf + (wn * 64 + j * 16 + mrow) * FBK + q * 8);
#pragma unroll
        for (int i = 0; i < 4; ++i)
#pragma unroll
            for (int j = 0; j < 4; ++j)
                acc[i][j] = __builtin_amdgcn_mfma_f32_16x16x32_bf16(a[i], b[j], acc[i][j], 0, 0, 0);
        __syncthreads();
    }

#pragma unroll
    for (int i = 0; i < 4; ++i) {
#pragma unroll
        for (int r = 0; r < 4; ++r) {
            size_t grow = rowbase + wm * 64 + i * 16 + q * 4 + r;
            if (mask[grow]) {
#pragma unroll
                for (int j = 0; j < 4; ++j) {
                    float g = gelu_fast(acc[i][j][r]);
                    int col = colbase + wn * 64 + j * 16 + mrow;
                    out[grow * DIM + col] = g;
                }
            }
        }
    }
}

// ---------- 5) pass-through for unselected tokens via compacted index list ----------
__global__ __launch_bounds__(256) void passthrough_idx_kernel(const float* __restrict__ x,
                                                              const int* __restrict__ unsel_idx,
                                                              float* __restrict__ out) {
    int tok = unsel_idx[blockIdx.x];
    size_t c = (size_t)tok * (DIM / 4) + threadIdx.x;  // float4 units, 256/token
    ((float4*)out)[c] = ((const float4*)x)[c];
}

extern "C" void kernel_launch(void* const* d_in, const int* in_sizes, int n_in,
                              void* d_out, int out_size, void* d_ws, size_t ws_size,
                              hipStream_t stream) {
    const float* x  = (const float*)d_in[0];   // [4,8192,1024] fp32
    const float* wr = (const float*)d_in[1];   // [1024] fp32
    const float* wb = (const float*)d_in[2];   // [1024,1024] fp32
    float* out = (float*)d_out;

    char* ws = (char*)d_ws;
    float* scores    = (float*)ws;                            // 128 KB
    int*   mask      = (int*)(ws + (size_t)NTOK * 4);         // 128 KB
    int*   sel_idx   = (int*)(ws + (size_t)NTOK * 8);         // 96 KB
    int*   unsel_idx = (int*)(ws + (size_t)NTOK * 8 + (size_t)NSEL * 4);  // 32 KB
    char*  after_idx = ws + (size_t)NTOK * 8 + (size_t)NTOK * 4;          // = 384 KB
    u16*   WT        = (u16*)after_idx;                       // 2 MB bf16
    u16*   Xb        = (u16*)(after_idx + (size_t)DIM * DIM * 2);  // 64 MB bf16

    const size_t need_ws = (size_t)NTOK * 12 + (size_t)DIM * DIM * 2
                         + (size_t)NTOK * DIM * 2;
    const bool big = (ws_size >= need_ws);

    score_kernel<<<NTOK / 4, 256, 0, stream>>>(x, wr, scores, big ? Xb : nullptr);
    select_kernel<<<BATCH, 1024, 0, stream>>>(scores, mask, sel_idx, unsel_idx);
    transpose_kernel<<<dim3(DIM / 32, DIM / 32), 256, 0, stream>>>(wb, WT);
    if (big) {
        gemm_idx_kernel<<<dim3(NSEL / PM, DIM / PN), 256, 0, stream>>>(Xb, WT, sel_idx, out);
    } else {
        gemm_f32_kernel<<<dim3(NTOK / FBM, DIM / FBN), 256, 0, stream>>>(x, WT, mask, out);
    }
    passthrough_idx_kernel<<<NUNSEL, 256, 0, stream>>>(x, unsel_idx, out);
}